// Round 1
// baseline (1119.630 us; speedup 1.0000x reference)
//
#include <hip/hip_runtime.h>
#include <hip/hip_bf16.h>

using bf16 = __hip_bfloat16;
typedef __attribute__((ext_vector_type(8))) short bf16x8;
typedef __attribute__((ext_vector_type(4))) float f32x4;

#define T_STEPS 256
#define BATCH   256
#define D_IN    256
#define HID     512
#define M_ROWS  (T_STEPS*BATCH)   // 65536

// ---------------------------------------------------------------------------
// W decomposition: fp32 W[K][512] -> Wt[512][3K] bf16 (hi, mid, lo residuals).
// hi+mid+lo reconstructs >=24 mantissa bits => fp32-exact GEMM via 3x bf16 MFMA.
// ---------------------------------------------------------------------------
__global__ __launch_bounds__(256) void decomp_kernel(
    const float* __restrict__ W, bf16* __restrict__ Wt, int kbits)
{
  int idx = blockIdx.x * 256 + threadIdx.x;
  int K = 1 << kbits;
  int k = idx & (K - 1);
  int n = idx >> kbits;
  float wv = W[(size_t)k * HID + n];
  bf16 hi = __float2bfloat16(wv);
  float r1 = wv - __bfloat162float(hi);
  bf16 mid = __float2bfloat16(r1);
  float r2 = r1 - __bfloat162float(mid);
  bf16 lo = __float2bfloat16(r2);
  size_t base = (size_t)n * (3 * K) + k;   // [n][segment*K + k], K-minor
  Wt[base]       = hi;
  Wt[base + K]   = mid;
  Wt[base + 2*K] = lo;
}

// ---------------------------------------------------------------------------
// Convert fp32 spike input {0,1} -> bf16 (exact).
// ---------------------------------------------------------------------------
__global__ __launch_bounds__(256) void cvt_kernel(
    const float* __restrict__ in, bf16* __restrict__ out)
{
  const int n4 = (T_STEPS * BATCH * D_IN) / 4;
  for (int i = blockIdx.x * 256 + threadIdx.x; i < n4; i += gridDim.x * 256) {
    float4 v = *(const float4*)(in + (size_t)i * 4);
    out[(size_t)i*4 + 0] = __float2bfloat16(v.x);
    out[(size_t)i*4 + 1] = __float2bfloat16(v.y);
    out[(size_t)i*4 + 2] = __float2bfloat16(v.z);
    out[(size_t)i*4 + 3] = __float2bfloat16(v.w);
  }
}

// ---------------------------------------------------------------------------
// GEMM: A[M][Ksrc] bf16 (spikes)  x  Wt[512][Ke] bf16 (K-minor, Ke = 3*Ksrc)
//   -> C[M][512] fp32.   A is logically replicated 3x along K (akb = kt*64 % Ksrc).
// m97-style: 128x128 tile, BK=64, 4 waves (2x2), 16x16x32 MFMA, global_load_lds(16),
// T2 XOR-swizzle applied to SOURCE (stage) and READ (both-sides, rule #21).
// ---------------------------------------------------------------------------
__global__ __launch_bounds__(256) void gemm_kernel(
    const bf16* __restrict__ A, int kmask,        // kmask = Ksrc-1 (pow2)
    const bf16* __restrict__ Bt, int Ke,
    float* __restrict__ C)
{
  __shared__ bf16 As[128 * 64];   // [row][k], 128B rows (linear; swizzle via addr)
  __shared__ bf16 Bs[128 * 64];

  const int tid = threadIdx.x;
  const int l   = tid & 63;
  const int w   = tid >> 6;          // wave 0..3
  const int wr  = w >> 1, wc = w & 1;
  const int bn  = blockIdx.x & 3;    // N/128 = 4
  const int bm  = blockIdx.x >> 2;   // M/128 = 512
  const int trow = tid >> 3;         // 0..31
  const int tc8  = tid & 7;          // 16B chunk within a 128B row
  const int Ksrc = kmask + 1;
  const int lrow16 = l & 15;
  const int lk8    = (l >> 4) * 8;   // k element offset of this lane's frag

  f32x4 acc[4][4] = {};

  for (int kt = 0; kt < Ke / 64; ++kt) {
    const int akb = (kt * 64) & kmask;   // A column base (replicated segments)
    const int bkb = kt * 64;
    #pragma unroll
    for (int i = 0; i < 4; ++i) {
      const int row = i * 32 + trow;
      const int c8  = tc8 ^ (row & 7);   // inverse-swizzled SOURCE chunk
      const bf16* ga = A  + (size_t)(bm * 128 + row) * Ksrc + akb + c8 * 8;
      const bf16* gb = Bt + (size_t)(bn * 128 + row) * Ke  + bkb + c8 * 8;
      __builtin_amdgcn_global_load_lds(
          (const __attribute__((address_space(1))) void*)ga,
          (__attribute__((address_space(3))) void*)&As[row * 64 + tc8 * 8],
          16, 0, 0);
      __builtin_amdgcn_global_load_lds(
          (const __attribute__((address_space(1))) void*)gb,
          (__attribute__((address_space(3))) void*)&Bs[row * 64 + tc8 * 8],
          16, 0, 0);
    }
    __syncthreads();   // compiler drains vmcnt before s_barrier

    #pragma unroll
    for (int ks = 0; ks < 2; ++ks) {
      bf16x8 af[4], bfr[4];
      #pragma unroll
      for (int mi = 0; mi < 4; ++mi) {
        int row = wr * 64 + mi * 16 + lrow16;
        int byt = row * 128 + (ks * 32 + lk8) * 2;
        byt ^= (row & 7) << 4;           // swizzled READ (same involution)
        af[mi] = *(const bf16x8*)((const char*)As + byt);
      }
      #pragma unroll
      for (int ni = 0; ni < 4; ++ni) {
        int row = wc * 64 + ni * 16 + lrow16;
        int byt = row * 128 + (ks * 32 + lk8) * 2;
        byt ^= (row & 7) << 4;
        bfr[ni] = *(const bf16x8*)((const char*)Bs + byt);
      }
      #pragma unroll
      for (int mi = 0; mi < 4; ++mi)
        #pragma unroll
        for (int ni = 0; ni < 4; ++ni)
          acc[mi][ni] = __builtin_amdgcn_mfma_f32_16x16x32_bf16(
              af[mi], bfr[ni], acc[mi][ni], 0, 0, 0);
    }
    __syncthreads();
  }

  // Epilogue: C/D layout col = lane&15, row = (lane>>4)*4 + reg  [m89-verified]
  const int rg = (l >> 4) * 4;
  #pragma unroll
  for (int mi = 0; mi < 4; ++mi) {
    #pragma unroll
    for (int j = 0; j < 4; ++j) {
      int row = bm * 128 + wr * 64 + mi * 16 + rg + j;
      float* crow = C + (size_t)row * HID + bn * 128 + wc * 64 + lrow16;
      #pragma unroll
      for (int ni = 0; ni < 4; ++ni)
        crow[ni * 16] = acc[mi][ni][j];
    }
  }
}

// ---------------------------------------------------------------------------
// BN stats: per (t,h) mean/var over b (biased), folded with gamma/beta into
// scale/shift (bias b_i cancels in BN).  ss[t*512+h] = {scale, shift} float2.
// ---------------------------------------------------------------------------
__global__ __launch_bounds__(256) void stats_kernel(
    const float* __restrict__ X,    // [T*B][512], row = t*256+b
    const float* __restrict__ g, const float* __restrict__ bb,
    float2* __restrict__ ss)        // [T][512]
{
  __shared__ float s_s[256], s_q[256];
  const int t  = blockIdx.x >> 2;
  const int hb = (blockIdx.x & 3) * 128;
  const int h    = threadIdx.x & 127;
  const int half = threadIdx.x >> 7;
  const float* base = X + (size_t)t * (BATCH * HID) + hb + h;
  float s = 0.f, q = 0.f;
  for (int b = half * 128; b < half * 128 + 128; ++b) {
    float v = base[(size_t)b * HID];
    s += v;
    q = fmaf(v, v, q);
  }
  s_s[threadIdx.x] = s; s_q[threadIdx.x] = q;
  __syncthreads();
  if (half == 0) {
    s += s_s[threadIdx.x + 128];
    q += s_q[threadIdx.x + 128];
    float mu  = s * (1.f / 256.f);
    float var = fmaf(-mu, mu, q * (1.f / 256.f));
    float ve  = var + 1e-5f;
    float r   = rsqrtf(ve);
    r = r * (1.5f - 0.5f * ve * r * r);     // Newton refine -> ~fp32-exact
    float sc = g[hb + h] * r;
    float sh = fmaf(-mu, sc, bb[hb + h]);
    ss[t * HID + hb + h] = make_float2(sc, sh);
  }
}

// ---------------------------------------------------------------------------
// LIF scan: thread = (b,h); sequential over t.  Writes mem trace (fp32, d_out)
// and spikes (bf16, exact 0/1) for the next layer's GEMM.
// ---------------------------------------------------------------------------
__global__ __launch_bounds__(256) void scan_kernel(
    const float* __restrict__ X,        // [T*B][512]
    const float2* __restrict__ ss,      // [T][512]
    float beta,
    float* __restrict__ mem_out,        // [T*B][512] (into d_out)
    bf16* __restrict__ spk)             // [T*B][512]
{
  const int idx = blockIdx.x * 256 + threadIdx.x;   // 131072 threads
  const int h = idx & (HID - 1);
  const int b = idx >> 9;
  const float* x = X + (size_t)b * HID + h;
  float* mo = mem_out + (size_t)b * HID + h;
  bf16* sp = spk + (size_t)b * HID + h;
  const bf16 ONE  = __float2bfloat16(1.0f);
  const bf16 ZERO = __float2bfloat16(0.0f);
  float m = 0.f;
  #pragma unroll 4
  for (int t = 0; t < T_STEPS; ++t) {
    float xp = x[(size_t)t * (BATCH * HID)];
    float2 v = ss[t * HID + h];
    float xn = fmaf(xp, v.x, v.y);
    float reset = (m > 1.f) ? 1.f : 0.f;
    m = fmaf(beta, m, xn - reset);
    mo[(size_t)t * (BATCH * HID)] = m;
    sp[(size_t)t * (BATCH * HID)] = (m > 1.f) ? ONE : ZERO;
  }
}

// ---------------------------------------------------------------------------
// Output layer: out[row][3] = spk2[row][:] @ Wo[512][3] + bo.  One wave per row;
// Wo rows held in registers (24 floats/lane), butterfly reduce over 64 lanes.
// ---------------------------------------------------------------------------
__global__ __launch_bounds__(256) void out_kernel(
    const bf16* __restrict__ spk,   // [65536][512]
    const float* __restrict__ Wo,   // [512][3]
    const float* __restrict__ bo,
    float* __restrict__ out)        // [65536][3]
{
  const int l = threadIdx.x & 63;
  const int w = threadIdx.x >> 6;
  float wreg[8][3];
  #pragma unroll
  for (int e = 0; e < 8; ++e)
    #pragma unroll
    for (int j = 0; j < 3; ++j)
      wreg[e][j] = Wo[(8 * l + e) * 3 + j];
  const float b0 = bo[0], b1 = bo[1], b2 = bo[2];

  #pragma unroll 1
  for (int it = 0; it < 16; ++it) {
    const int row = blockIdx.x * 64 + it * 4 + w;
    uint4 sv = ((const uint4*)(spk + (size_t)row * HID))[l];
    float s0 = 0.f, s1 = 0.f, s2 = 0.f;
    const unsigned ue[4] = {sv.x, sv.y, sv.z, sv.w};
    #pragma unroll
    for (int q = 0; q < 4; ++q) {
      float fe = __uint_as_float(ue[q] << 16);            // even elem (low half)
      float fo = __uint_as_float(ue[q] & 0xffff0000u);    // odd elem
      s0 = fmaf(fe, wreg[2*q][0], s0);
      s1 = fmaf(fe, wreg[2*q][1], s1);
      s2 = fmaf(fe, wreg[2*q][2], s2);
      s0 = fmaf(fo, wreg[2*q+1][0], s0);
      s1 = fmaf(fo, wreg[2*q+1][1], s1);
      s2 = fmaf(fo, wreg[2*q+1][2], s2);
    }
    #pragma unroll
    for (int off = 32; off; off >>= 1) {
      s0 += __shfl_xor(s0, off);
      s1 += __shfl_xor(s1, off);
      s2 += __shfl_xor(s2, off);
    }
    if (l == 0) {
      out[(size_t)row * 3 + 0] = s0 + b0;
      out[(size_t)row * 3 + 1] = s1 + b1;
      out[(size_t)row * 3 + 2] = s2 + b2;
    }
  }
}

// ---------------------------------------------------------------------------
extern "C" void kernel_launch(void* const* d_in, const int* in_sizes, int n_in,
                              void* d_out, int out_size, void* d_ws, size_t ws_size,
                              hipStream_t stream) {
  const float* spike_in = (const float*)d_in[0];
  const float* W0 = (const float*)d_in[1];
  const float* g0 = (const float*)d_in[3];
  const float* bb0 = (const float*)d_in[4];
  const float* W1 = (const float*)d_in[5];
  const float* g1 = (const float*)d_in[7];
  const float* bb1 = (const float*)d_in[8];
  const float* W2 = (const float*)d_in[9];
  const float* g2 = (const float*)d_in[11];
  const float* bb2 = (const float*)d_in[12];
  const float* Wo = (const float*)d_in[13];
  const float* bo = (const float*)d_in[14];

  // workspace layout (bytes)
  char* ws = (char*)d_ws;
  const size_t OFF_WT0 = 0;            // 512*768*2  = 786432
  const size_t OFF_WT1 = 786432;       // 512*1536*2 = 1572864
  const size_t OFF_WT2 = 2359296;      // 1572864
  const size_t OFF_SS  = 3932160;      // 256*512*8  = 1048576
  const size_t OFF_SA  = 4980736;      // 65536*512*2 = 67108864
  const size_t OFF_SB  = 72089600;     // 67108864
  const size_t OFF_X   = 139198464;    // 65536*512*4 = 134217728
  const size_t NEEDED  = 273416192;
  if (ws_size < NEEDED) return;        // fail loudly via poisoned output

  bf16*   Wt0  = (bf16*)(ws + OFF_WT0);
  bf16*   Wt1  = (bf16*)(ws + OFF_WT1);
  bf16*   Wt2  = (bf16*)(ws + OFF_WT2);
  float2* ssb  = (float2*)(ws + OFF_SS);
  bf16*   spkA = (bf16*)(ws + OFF_SA);
  bf16*   spkB = (bf16*)(ws + OFF_SB);
  float*  Xp   = (float*)(ws + OFF_X);

  float* out0 = (float*)d_out;                 // [T,B,3]
  float* mem0 = out0 + 196608;                 // [T,B,512]
  float* mem1 = mem0 + 33554432;
  float* mem2 = mem1 + 33554432;

  decomp_kernel<<<512,  256, 0, stream>>>(W0, Wt0, 8);
  decomp_kernel<<<1024, 256, 0, stream>>>(W1, Wt1, 9);
  decomp_kernel<<<1024, 256, 0, stream>>>(W2, Wt2, 9);
  cvt_kernel<<<2048, 256, 0, stream>>>(spike_in, spkA);

  // layer 0
  gemm_kernel<<<2048, 256, 0, stream>>>(spkA, 255, Wt0, 768, Xp);
  stats_kernel<<<1024, 256, 0, stream>>>(Xp, g0, bb0, ssb);
  scan_kernel<<<512, 256, 0, stream>>>(Xp, ssb, 0.90f, mem0, spkB);
  // layer 1
  gemm_kernel<<<2048, 256, 0, stream>>>(spkB, 511, Wt1, 1536, Xp);
  stats_kernel<<<1024, 256, 0, stream>>>(Xp, g1, bb1, ssb);
  scan_kernel<<<512, 256, 0, stream>>>(Xp, ssb, 0.95f, mem1, spkA);
  // layer 2
  gemm_kernel<<<2048, 256, 0, stream>>>(spkA, 511, Wt2, 1536, Xp);
  stats_kernel<<<1024, 256, 0, stream>>>(Xp, g2, bb2, ssb);
  scan_kernel<<<512, 256, 0, stream>>>(Xp, ssb, 0.99f, mem2, spkB);
  // output fc
  out_kernel<<<1024, 256, 0, stream>>>(spkB, Wo, bo, out0);
}